// Round 12
// baseline (42.953 us; speedup 1.0000x reference)
//
#include <hip/hip_runtime.h>
#include <hip/hip_bf16.h>

// YOLO layer decode: x (16, 340, 76, 76) f32 -> out (16, 4*76*76, 85) f32.
// 4 y-rows per block: every per-channel read chunk is 1216 B = exactly 19
// cache lines, 64B-aligned (no split lines at all); 103 KB contiguous store
// run per block. Bijective chunked XCD swizzle keeps memory-adjacent blocks
// on one XCD's L2. 103 KB LDS -> 1 block/CU x 16 waves (50% cap — shown
// non-binding in rounds 10/11).

constexpr int BS = 16;
constexpr int NA = 4;
constexpr int NC = 85;
constexpr int FY = 76;
constexpr int FX = 76;
constexpr int PLANE = FY * FX;        // 5776
constexpr int TILE  = NC * FX;        // 6460 floats per slab (one y)
constexpr int YG    = 4;              // y rows per block
constexpr int CHUNK = YG * FX;        // 304 floats = 1216 B per channel chunk
constexpr int RVC   = CHUNK / 4;      // 76 float4s per channel chunk
constexpr int QPR   = FX / 4;         // 19 quads per y-row
constexpr int NV2   = NC * RVC;       // 6460 float4s per block
constexpr int NTHR  = 1024;
constexpr int KFULL = NV2 / NTHR;     // 6 full passes
constexpr int TAIL2 = NV2 - KFULL * NTHR;   // 316 (threads 0..315)
constexpr int NBLK  = BS * NA * (FY / YG);  // 1216
constexpr int PER_XCD = NBLK / 8;     // 152
constexpr float STRIDE_F = 8.0f;
constexpr float LOG2E = 1.4426950408889634f;

__device__ __forceinline__ float fast_sigmoid(float v) {
    return __builtin_amdgcn_rcpf(1.0f + __builtin_amdgcn_exp2f(v * -LOG2E));
}
__device__ __forceinline__ float fast_exp(float v) {
    return __builtin_amdgcn_exp2f(v * LOG2E);
}

// Transform one float4 of channel c at quad j (j in [0,76)), scatter to
// lds[pos][c] where pos = 4j..4j+3 spans the 4-row x-range.
__device__ __forceinline__ void xform_scatter(float* __restrict__ lds,
                                              int c, int j, float4 v,
                                              float ax, float ay, float y0f) {
    const float vv[4] = {v.x, v.y, v.z, v.w};
    const int pos0 = 4 * j;
    const int ylocal = j / QPR;               // quad never straddles y-rows
    const int xi0 = pos0 - ylocal * FX;
    float* __restrict__ dst = &lds[pos0 * NC + c];
    if (c >= 4) {
        #pragma unroll
        for (int kk = 0; kk < 4; ++kk)
            dst[kk * NC] = fast_sigmoid(vv[kk]);
    } else if (c == 0) {
        #pragma unroll
        for (int kk = 0; kk < 4; ++kk)
            dst[kk * NC] = fast_sigmoid(vv[kk]) * STRIDE_F
                         + (float)(xi0 + kk) * STRIDE_F;
    } else if (c == 1) {
        const float yf = y0f + (float)ylocal;
        #pragma unroll
        for (int kk = 0; kk < 4; ++kk)
            dst[kk * NC] = fast_sigmoid(vv[kk]) * STRIDE_F + yf * STRIDE_F;
    } else if (c == 2) {
        #pragma unroll
        for (int kk = 0; kk < 4; ++kk)
            dst[kk * NC] = fast_exp(vv[kk]) * ax;
    } else {
        #pragma unroll
        for (int kk = 0; kk < 4; ++kk)
            dst[kk * NC] = fast_exp(vv[kk]) * ay;
    }
}

__global__ __launch_bounds__(NTHR)
void yolo_decode_kernel(const float* __restrict__ x,
                        const float* __restrict__ anchors,
                        float* __restrict__ out) {
    __shared__ float lds[NC * CHUNK];   // 25840 floats = 103360 B

    // Bijective chunked XCD swizzle: XCD k (= blockIdx%8 round-robin) gets
    // orig in [k*152,(k+1)*152): whole ba panels, y-groups in order.
    const int B    = blockIdx.x;
    const int orig = (B & 7) * PER_XCD + (B >> 3);
    const int yp   = orig % (FY / YG);
    const int ba   = orig / (FY / YG);
    const int a    = ba % NA;

    const float ax  = anchors[a * 2 + 0] * STRIDE_F;
    const float ay  = anchors[a * 2 + 1] * STRIDE_F;
    const float y0f = (float)(YG * yp);

    const float* __restrict__ inbase = x + (size_t)ba * NC * PLANE + (size_t)yp * CHUNK;
    const int t = threadIdx.x;

    // --- Load phase: issue all 6-7 loads back-to-back. ---
    float4 v[KFULL + 1];
    #pragma unroll
    for (int k = 0; k < KFULL; ++k) {
        const int i = t + NTHR * k;
        const int c = i / RVC;            // magic-mul
        const int j = i - c * RVC;
        v[k] = *(const float4*)(inbase + (size_t)c * PLANE + j * 4);
    }
    if (t < TAIL2) {
        const int i = KFULL * NTHR + t;
        const int c = i / RVC;
        const int j = i - c * RVC;
        v[KFULL] = *(const float4*)(inbase + (size_t)c * PLANE + j * 4);
    }

    asm volatile("" ::: "memory");   // keep loads grouped above the transforms

    // --- Transform + LDS scatter. ---
    #pragma unroll
    for (int k = 0; k < KFULL; ++k) {
        const int i = t + NTHR * k;
        const int c = i / RVC;
        const int j = i - c * RVC;
        xform_scatter(lds, c, j, v[k], ax, ay, y0f);
    }
    if (t < TAIL2) {
        const int i = KFULL * NTHR + t;
        const int c = i / RVC;
        const int j = i - c * RVC;
        xform_scatter(lds, c, j, v[KFULL], ax, ay, y0f);
    }

    __syncthreads();

    // --- Store: 4 slabs = 25840 contiguous floats (6460 float4s). ---
    const float4* __restrict__ ldsv = (const float4*)lds;
    float4* __restrict__ ov = (float4*)(out + (size_t)(ba * FY + YG * yp) * TILE);
    #pragma unroll
    for (int k = 0; k < KFULL; ++k)
        ov[t + NTHR * k] = ldsv[t + NTHR * k];
    if (t < TAIL2)
        ov[KFULL * NTHR + t] = ldsv[KFULL * NTHR + t];
}

extern "C" void kernel_launch(void* const* d_in, const int* in_sizes, int n_in,
                              void* d_out, int out_size, void* d_ws, size_t ws_size,
                              hipStream_t stream) {
    const float* x       = (const float*)d_in[0];
    const float* anchors = (const float*)d_in[1];
    float* out           = (float*)d_out;

    yolo_decode_kernel<<<NBLK, NTHR, 0, stream>>>(x, anchors, out);
}